// Round 1
// baseline (23730.774 us; speedup 1.0000x reference)
//
#include <hip/hip_runtime.h>

#define B_ 64
#define T_ 2048
#define I_ 256
#define H_ 256
#define G3 768

// ---------------- Phase 1 ----------------
// gi[t][b][col] = x[b,t,:] . W_ih[col,:] + b_ih[col] + (col<512 ? b_hh[col] : 0)
// One block per (t, n-tile of 64). M-tile = the 64 batch rows at this t.
__global__ __launch_bounds__(256) void gi_gemm(
    const float* __restrict__ x, const float* __restrict__ Wih,
    const float* __restrict__ bih, const float* __restrict__ bhh,
    float* __restrict__ gi, int t0)
{
  const int t  = t0 + blockIdx.x;
  const int n0 = blockIdx.y * 64;
  __shared__ float As[32][68];
  __shared__ float Bs[32][68];
  const int tid = threadIdx.x;
  const int ty = tid >> 4, tx = tid & 15;
  const int lr = tid >> 3;          // 0..31
  const int lk = (tid & 7) << 2;    // 0,4,..,28
  float acc[4][4] = {};

  for (int kc = 0; kc < I_; kc += 32) {
    float4 a0 = *(const float4*)(x + ((size_t)lr        * T_ + t) * I_ + kc + lk);
    float4 a1 = *(const float4*)(x + ((size_t)(lr + 32) * T_ + t) * I_ + kc + lk);
    float4 b0 = *(const float4*)(Wih + (size_t)(n0 + lr)      * I_ + kc + lk);
    float4 b1 = *(const float4*)(Wih + (size_t)(n0 + lr + 32) * I_ + kc + lk);
    __syncthreads();
    As[lk+0][lr]    = a0.x; As[lk+1][lr]    = a0.y; As[lk+2][lr]    = a0.z; As[lk+3][lr]    = a0.w;
    As[lk+0][lr+32] = a1.x; As[lk+1][lr+32] = a1.y; As[lk+2][lr+32] = a1.z; As[lk+3][lr+32] = a1.w;
    Bs[lk+0][lr]    = b0.x; Bs[lk+1][lr]    = b0.y; Bs[lk+2][lr]    = b0.z; Bs[lk+3][lr]    = b0.w;
    Bs[lk+0][lr+32] = b1.x; Bs[lk+1][lr+32] = b1.y; Bs[lk+2][lr+32] = b1.z; Bs[lk+3][lr+32] = b1.w;
    __syncthreads();
    #pragma unroll
    for (int kk = 0; kk < 32; ++kk) {
      float4 av = *(const float4*)(&As[kk][ty << 2]);
      float4 bv = *(const float4*)(&Bs[kk][tx << 2]);
      float av_[4] = {av.x, av.y, av.z, av.w};
      float bv_[4] = {bv.x, bv.y, bv.z, bv.w};
      #pragma unroll
      for (int i = 0; i < 4; ++i)
        #pragma unroll
        for (int u = 0; u < 4; ++u)
          acc[i][u] = fmaf(av_[i], bv_[u], acc[i][u]);
    }
  }

  const int colb = n0 + (tx << 2);
  float4 bi = *(const float4*)(bih + colb);
  float4 bh = *(const float4*)(bhh + colb);
  float4 badd;
  badd.x = bi.x + (colb + 0 < 512 ? bh.x : 0.f);
  badd.y = bi.y + (colb + 1 < 512 ? bh.y : 0.f);
  badd.z = bi.z + (colb + 2 < 512 ? bh.z : 0.f);
  badd.w = bi.w + (colb + 3 < 512 ? bh.w : 0.f);
  float* gout = gi + (size_t)blockIdx.x * 64 * G3;
  #pragma unroll
  for (int i = 0; i < 4; ++i) {
    int bb = (ty << 2) + i;
    float4 o;
    o.x = acc[i][0] + badd.x; o.y = acc[i][1] + badd.y;
    o.z = acc[i][2] + badd.z; o.w = acc[i][3] + badd.w;
    *(float4*)(gout + (size_t)bb * G3 + colb) = o;
  }
}

// ---------------- Phase 2 ----------------
// One block per batch element. 1024 threads: (j = tid>>2) in [0,256), (s = tid&3) k-slice.
// Thread (j,s) holds W_hh rows {j, j+256, j+512}, cols [64s, 64s+64) in 192 VGPRs.
// h double-buffered in LDS (padded 68/slice), one barrier per step, s-reduction via shfl_xor.
__global__ __launch_bounds__(1024, 4) void gru_seq(
    const float* __restrict__ gi, const float* __restrict__ att,
    const int* __restrict__ lengths, const float* __restrict__ Whh,
    const float* __restrict__ bhh, float* __restrict__ hws,
    float* __restrict__ out, int t0, int t1)
{
  const int b   = blockIdx.x;
  const int tid = threadIdx.x;
  const int j = tid >> 2;
  const int s = tid & 3;
  __shared__ float hbuf[2][272];   // 4 slices * 68 floats, double buffered

  // Preload W_hh fragments into registers.
  float w[192];
  {
    const float* wp = Whh + (size_t)j * H_ + s * 64;
    #pragma unroll
    for (int g = 0; g < 3; ++g)
      #pragma unroll
      for (int q = 0; q < 16; ++q) {
        float4 v = *(const float4*)(wp + (size_t)g * (256 * H_) + (q << 2));
        w[g*64 + q*4 + 0] = v.x; w[g*64 + q*4 + 1] = v.y;
        w[g*64 + q*4 + 2] = v.z; w[g*64 + q*4 + 3] = v.w;
      }
  }
  float bhn = 0.f, h_reg = 0.f;
  if (s == 0) {
    bhn = bhh[512 + j];
    h_reg = (t0 > 0) ? hws[b * H_ + j] : 0.f;
  }
  if (tid < 272) {
    int ss = tid / 68, ii = tid % 68;
    hbuf[0][tid] = (ii < 64 && t0 > 0) ? hws[b * H_ + ss * 64 + ii] : 0.f;
    hbuf[1][tid] = 0.f;
  }
  int len = lengths[b]; if (len > t1) len = t1;
  __syncthreads();

  // Software-pipelined gi/att loads (held one step ahead).
  float c_gvr = 0.f, c_gvz = 0.f, c_gvn = 0.f, c_wat = 0.f;
  if (t0 < len) {
    const float* gb = gi + (size_t)b * G3;   // (t-t0)==0
    if (s == 0) { c_gvr = gb[j]; c_gvn = gb[512 + j]; }
    if (s == 1) { c_gvz = gb[256 + j]; }
    c_wat = att[(size_t)b * T_ + t0];
  }

  int p = 0;
  for (int t = t0; t < len; ++t) {
    float n_gvr = 0.f, n_gvz = 0.f, n_gvn = 0.f, n_wat = 0.f;
    if (t + 1 < len) {
      const float* gb = gi + ((size_t)(t + 1 - t0) * 64 + b) * G3;
      if (s == 0) { n_gvr = gb[j]; n_gvn = gb[512 + j]; }
      if (s == 1) { n_gvz = gb[256 + j]; }
      n_wat = att[(size_t)b * T_ + t + 1];
    }

    float acc0 = 0.f, acc1 = 0.f, acc2 = 0.f;
    const float* hb = &hbuf[p][s * 68];
    #pragma unroll
    for (int q = 0; q < 16; ++q) {
      float4 hv = *(const float4*)(hb + (q << 2));
      float hv_[4] = {hv.x, hv.y, hv.z, hv.w};
      #pragma unroll
      for (int u = 0; u < 4; ++u) {
        acc0 = fmaf(w[      q*4 + u], hv_[u], acc0);
        acc1 = fmaf(w[ 64 + q*4 + u], hv_[u], acc1);
        acc2 = fmaf(w[128 + q*4 + u], hv_[u], acc2);
      }
    }
    // fold gi for r/z before the s-reduction (nonzero only on the loading lane)
    acc0 += c_gvr;
    acc1 += c_gvz;
    acc0 += __shfl_xor(acc0, 1); acc0 += __shfl_xor(acc0, 2);
    acc1 += __shfl_xor(acc1, 1); acc1 += __shfl_xor(acc1, 2);
    acc2 += __shfl_xor(acc2, 1); acc2 += __shfl_xor(acc2, 2);

    if (s == 0) {
      float r = 1.f / (1.f + __expf(-acc0));
      float z = 1.f / (1.f + __expf(-acc1));
      float e2 = __expf(2.f * (c_gvn + r * (acc2 + bhn)));
      float nn = 1.f - 2.f / (e2 + 1.f);      // tanh
      float hnew = (1.f - z) * nn + z * h_reg;
      h_reg = c_wat * hnew + (1.f - c_wat) * h_reg;
      hbuf[p ^ 1][(j >> 6) * 68 + (j & 63)] = h_reg;
    }
    __syncthreads();
    p ^= 1;
    c_gvr = n_gvr; c_gvz = n_gvz; c_gvn = n_gvn; c_wat = n_wat;
  }

  if (s == 0) {
    hws[b * H_ + j] = h_reg;
    if (t1 == T_) out[b * H_ + j] = h_reg;
  }
}

extern "C" void kernel_launch(void* const* d_in, const int* in_sizes, int n_in,
                              void* d_out, int out_size, void* d_ws, size_t ws_size,
                              hipStream_t stream)
{
  const float* x       = (const float*)d_in[0];
  const float* att     = (const float*)d_in[1];
  const int*   lengths = (const int*)d_in[2];
  const float* Wih     = (const float*)d_in[3];
  const float* Whh     = (const float*)d_in[4];
  const float* bih     = (const float*)d_in[5];
  const float* bhh     = (const float*)d_in[6];
  float* out = (float*)d_out;

  float* hws = (float*)d_ws;                       // 64 KiB h state (chunked mode)
  float* gi  = (float*)((char*)d_ws + 65536);
  const size_t per_t = (size_t)B_ * G3 * sizeof(float);
  size_t avail = ws_size > 65536 ? ws_size - 65536 : 0;
  int Tc = (int)(avail / per_t);
  if (Tc > T_) Tc = T_;
  if (Tc < 1) Tc = 1;   // assume ws is at least ~256 KiB

  for (int t0 = 0; t0 < T_; t0 += Tc) {
    int t1 = t0 + Tc; if (t1 > T_) t1 = T_;
    dim3 g1(t1 - t0, G3 / 64);
    gi_gemm<<<g1, 256, 0, stream>>>(x, Wih, bih, bhh, gi, t0);
    gru_seq<<<B_, 1024, 0, stream>>>(gi, att, lengths, Whh, bhh, hws, out, t0, t1);
  }
}

// Round 2
// 20312.692 us; speedup vs baseline: 1.1683x; 1.1683x over previous
//
#include <hip/hip_runtime.h>

#define B_ 64
#define T_ 2048
#define I_ 256
#define H_ 256
#define G3 768

// ---------------- Phase 1 ---------------- (unchanged, works: ~0.75ms)
__global__ __launch_bounds__(256) void gi_gemm(
    const float* __restrict__ x, const float* __restrict__ Wih,
    const float* __restrict__ bih, const float* __restrict__ bhh,
    float* __restrict__ gi, int t0)
{
  const int t  = t0 + blockIdx.x;
  const int n0 = blockIdx.y * 64;
  __shared__ float As[32][68];
  __shared__ float Bs[32][68];
  const int tid = threadIdx.x;
  const int ty = tid >> 4, tx = tid & 15;
  const int lr = tid >> 3;
  const int lk = (tid & 7) << 2;
  float acc[4][4] = {};

  for (int kc = 0; kc < I_; kc += 32) {
    float4 a0 = *(const float4*)(x + ((size_t)lr        * T_ + t) * I_ + kc + lk);
    float4 a1 = *(const float4*)(x + ((size_t)(lr + 32) * T_ + t) * I_ + kc + lk);
    float4 b0 = *(const float4*)(Wih + (size_t)(n0 + lr)      * I_ + kc + lk);
    float4 b1 = *(const float4*)(Wih + (size_t)(n0 + lr + 32) * I_ + kc + lk);
    __syncthreads();
    As[lk+0][lr]    = a0.x; As[lk+1][lr]    = a0.y; As[lk+2][lr]    = a0.z; As[lk+3][lr]    = a0.w;
    As[lk+0][lr+32] = a1.x; As[lk+1][lr+32] = a1.y; As[lk+2][lr+32] = a1.z; As[lk+3][lr+32] = a1.w;
    Bs[lk+0][lr]    = b0.x; Bs[lk+1][lr]    = b0.y; Bs[lk+2][lr]    = b0.z; Bs[lk+3][lr]    = b0.w;
    Bs[lk+0][lr+32] = b1.x; Bs[lk+1][lr+32] = b1.y; Bs[lk+2][lr+32] = b1.z; Bs[lk+3][lr+32] = b1.w;
    __syncthreads();
    #pragma unroll
    for (int kk = 0; kk < 32; ++kk) {
      float4 av = *(const float4*)(&As[kk][ty << 2]);
      float4 bv = *(const float4*)(&Bs[kk][tx << 2]);
      float av_[4] = {av.x, av.y, av.z, av.w};
      float bv_[4] = {bv.x, bv.y, bv.z, bv.w};
      #pragma unroll
      for (int i = 0; i < 4; ++i)
        #pragma unroll
        for (int u = 0; u < 4; ++u)
          acc[i][u] = fmaf(av_[i], bv_[u], acc[i][u]);
    }
  }

  const int colb = n0 + (tx << 2);
  float4 bi = *(const float4*)(bih + colb);
  float4 bh = *(const float4*)(bhh + colb);
  float4 badd;
  badd.x = bi.x + (colb + 0 < 512 ? bh.x : 0.f);
  badd.y = bi.y + (colb + 1 < 512 ? bh.y : 0.f);
  badd.z = bi.z + (colb + 2 < 512 ? bh.z : 0.f);
  badd.w = bi.w + (colb + 3 < 512 ? bh.w : 0.f);
  float* gout = gi + (size_t)blockIdx.x * 64 * G3;
  #pragma unroll
  for (int i = 0; i < 4; ++i) {
    int bb = (ty << 2) + i;
    float4 o;
    o.x = acc[i][0] + badd.x; o.y = acc[i][1] + badd.y;
    o.z = acc[i][2] + badd.z; o.w = acc[i][3] + badd.w;
    *(float4*)(gout + (size_t)bb * G3 + colb) = o;
  }
}

// ---------------- Stream prep ----------------
// Pre-swizzle the streamed weight tier into per-iteration coalesced layout.
// 48 slots/step, slot i holds one float4 per thread: wstream[(i*512 + tid)*4].
// Thread (j=tid>>1, s=tid&1), chunk q (k = 128s+4q):
//   q<16 : slot q       = w_n[q]
//   q>=16: slot 2q-16   = w_z[q]   (z cols 40..127 streamed part: q>=16 -> col 64..127)
//          slot 2q-15   = w_n[q]
__global__ void prep_stream(const float* __restrict__ Whh, float* __restrict__ wstream)
{
  int idx = blockIdx.x * 256 + threadIdx.x;   // [0, 16384)
  int q  = idx >> 9;        // 0..31
  int t5 = idx & 511;       // tid in gru_seq
  int j = t5 >> 1, s = t5 & 1;
  int col = (s << 7) + (q << 2);
  float4 vn = *(const float4*)(Whh + (size_t)(512 + j) * H_ + col);
  int slot_n = (q < 16) ? q : (2 * q - 15);
  *(float4*)(wstream + ((size_t)slot_n * 512 + t5) * 4) = vn;
  if (q >= 16) {
    float4 vz = *(const float4*)(Whh + (size_t)(256 + j) * H_ + col);
    int slot_z = 2 * q - 16;
    *(float4*)(wstream + ((size_t)slot_z * 512 + t5) * 4) = vz;
  }
}

// ---------------- Phase 2 ----------------
// One block per batch. 512 threads: (j = tid>>1) in [0,256), (s = tid&1) k-half.
// Weight tiers per thread (rows j:r, 256+j:z, 512+j:n; k in [128s,128s+128)):
//   VGPR: w_r (32 f4) + w_z cols 0..39 (10 f4)      = 168 floats
//   LDS : w_z cols 40..63 (6 f4, [i][tid] layout)   = 24 floats (49 KB total)
//   L2  : w_z cols 64..127 + w_n (48 f4/step ring)  = 192 floats/step
__global__ __launch_bounds__(512, 2) void gru_seq(
    const float* __restrict__ gi, const float* __restrict__ att,
    const int* __restrict__ lengths, const float* __restrict__ Whh,
    const float* __restrict__ bhh, const float* __restrict__ wstream,
    float* __restrict__ hws, float* __restrict__ out, int t0, int t1)
{
  const int b   = blockIdx.x;
  const int tid = threadIdx.x;
  const int j = tid >> 1;
  const int s = tid & 1;
  const int kb = s << 7;

  __shared__ float wz_hi[6 * 512 * 4];   // 49152 B
  __shared__ float hbuf[2][264];         // 2 slices * 132 (pad 4), double buffered

  // ---- VGPR weight tier ----
  float4 wr[32], wzl[10];
  const float* rowr = Whh + (size_t)j * H_ + kb;
  const float* rowz = Whh + (size_t)(256 + j) * H_ + kb;
  #pragma unroll
  for (int q = 0; q < 32; ++q) wr[q] = *(const float4*)(rowr + (q << 2));
  #pragma unroll
  for (int q = 0; q < 10; ++q) wzl[q] = *(const float4*)(rowz + (q << 2));
  // ---- LDS weight tier ----
  #pragma unroll
  for (int i = 0; i < 6; ++i) {
    float4 v = *(const float4*)(rowz + 40 + (i << 2));
    *(float4*)(&wz_hi[((i << 9) + tid) << 2]) = v;
  }

  float bhn = 0.f, h_reg = 0.f;
  if (s == 0) {
    bhn = bhh[512 + j];
    h_reg = (t0 > 0) ? hws[b * H_ + j] : 0.f;
  }
  if (tid < 256) {
    float hv0 = (t0 > 0) ? hws[b * H_ + tid] : 0.f;
    hbuf[0][(tid >> 7) * 132 + (tid & 127)] = hv0;
  }
  int len = lengths[b]; if (len > t1) len = t1;
  __syncthreads();

  // ---- stream ring prologue: slots 0..7 in flight ----
  const float* wsb = wstream + (tid << 2);
  float4 sbuf[8];
  #pragma unroll
  for (int i = 0; i < 8; ++i) sbuf[i] = *(const float4*)(wsb + i * 2048);

  // ---- gi/att software pipeline (one step ahead) ----
  float c_gvr = 0.f, c_gvz = 0.f, c_gvn = 0.f, c_wat = 0.f;
  if (t0 < len) {
    const float* gb = gi + (size_t)b * G3;
    if (s == 0) { c_gvr = gb[j]; c_gvn = gb[512 + j]; }
    else        { c_gvz = gb[256 + j]; }
    c_wat = att[(size_t)b * T_ + t0];
  }

  int p = 0;
  for (int t = t0; t < len; ++t) {
    float n_gvr = 0.f, n_gvz = 0.f, n_gvn = 0.f, n_wat = 0.f;
    if (t + 1 < len) {
      const float* gb = gi + ((size_t)(t + 1 - t0) * 64 + b) * G3;
      if (s == 0) { n_gvr = gb[j]; n_gvn = gb[512 + j]; }
      else        { n_gvz = gb[256 + j]; }
      n_wat = att[(size_t)b * T_ + t + 1];
    }

    float accr = 0.f, accz = 0.f, accn = 0.f;
    const float* hb = &hbuf[p][s * 132];
    #pragma unroll
    for (int q = 0; q < 32; ++q) {
      float4 hv = *(const float4*)(hb + (q << 2));
      // r gate (VGPR)
      float4 rv = wr[q];
      accr = fmaf(rv.x, hv.x, accr); accr = fmaf(rv.y, hv.y, accr);
      accr = fmaf(rv.z, hv.z, accr); accr = fmaf(rv.w, hv.w, accr);
      // z gate (VGPR / LDS / stream)
      float4 zv;
      if (q < 10) {
        zv = wzl[q];
      } else if (q < 16) {
        zv = *(const float4*)(&wz_hi[(((q - 10) << 9) + tid) << 2]);
      } else {
        int iz = 2 * q - 16;
        zv = sbuf[iz & 7];
        int rz = iz + 8; if (rz >= 48) rz -= 48;
        sbuf[iz & 7] = *(const float4*)(wsb + rz * 2048);
      }
      accz = fmaf(zv.x, hv.x, accz); accz = fmaf(zv.y, hv.y, accz);
      accz = fmaf(zv.z, hv.z, accz); accz = fmaf(zv.w, hv.w, accz);
      // n gate (stream)
      int in_ = (q < 16) ? q : (2 * q - 15);
      float4 nv = sbuf[in_ & 7];
      { int rn = in_ + 8; if (rn >= 48) rn -= 48;
        sbuf[in_ & 7] = *(const float4*)(wsb + rn * 2048); }
      accn = fmaf(nv.x, hv.x, accn); accn = fmaf(nv.y, hv.y, accn);
      accn = fmaf(nv.z, hv.z, accn); accn = fmaf(nv.w, hv.w, accn);
    }

    // fold gi for r/z before the 2-lane reduce (each lives on one lane)
    accr += c_gvr;
    accz += c_gvz;
    accr += __shfl_xor(accr, 1);
    accz += __shfl_xor(accz, 1);
    accn += __shfl_xor(accn, 1);

    if (s == 0) {
      float r = 1.f / (1.f + __expf(-accr));
      float z = 1.f / (1.f + __expf(-accz));
      float e2 = __expf(2.f * (c_gvn + r * (accn + bhn)));
      float nn = 1.f - 2.f / (e2 + 1.f);      // tanh
      float hnew = (1.f - z) * nn + z * h_reg;
      h_reg = c_wat * hnew + (1.f - c_wat) * h_reg;
      hbuf[p ^ 1][(j >> 7) * 132 + (j & 127)] = h_reg;
    }
    __syncthreads();
    p ^= 1;
    c_gvr = n_gvr; c_gvz = n_gvz; c_gvn = n_gvn; c_wat = n_wat;
  }

  if (s == 0) {
    hws[b * H_ + j] = h_reg;
    if (t1 == T_) out[b * H_ + j] = h_reg;
  }
}

extern "C" void kernel_launch(void* const* d_in, const int* in_sizes, int n_in,
                              void* d_out, int out_size, void* d_ws, size_t ws_size,
                              hipStream_t stream)
{
  const float* x       = (const float*)d_in[0];
  const float* att     = (const float*)d_in[1];
  const int*   lengths = (const int*)d_in[2];
  const float* Wih     = (const float*)d_in[3];
  const float* Whh     = (const float*)d_in[4];
  const float* bih     = (const float*)d_in[5];
  const float* bhh     = (const float*)d_in[6];
  float* out = (float*)d_out;

  float* hws     = (float*)d_ws;                         // 64 KiB
  float* wstream = (float*)((char*)d_ws + 65536);        // 384 KiB (48*512*16 B)
  float* gi      = (float*)((char*)d_ws + 65536 + 393216);
  const size_t used0 = 65536 + 393216;
  const size_t per_t = (size_t)B_ * G3 * sizeof(float);
  size_t avail = ws_size > used0 ? ws_size - used0 : 0;
  int Tc = (int)(avail / per_t);
  if (Tc > T_) Tc = T_;
  if (Tc < 1) Tc = 1;

  prep_stream<<<64, 256, 0, stream>>>(Whh, wstream);

  for (int t0 = 0; t0 < T_; t0 += Tc) {
    int t1 = t0 + Tc; if (t1 > T_) t1 = T_;
    dim3 g1(t1 - t0, G3 / 64);
    gi_gemm<<<g1, 256, 0, stream>>>(x, Wih, bih, bhh, gi, t0);
    gru_seq<<<B_, 512, 0, stream>>>(gi, att, lengths, Whh, bhh, wstream, hws, out, t0, t1);
  }
}

// Round 3
// 5696.375 us; speedup vs baseline: 4.1659x; 3.5659x over previous
//
#include <hip/hip_runtime.h>
#include <stdint.h>

#define B_ 64
#define T_ 2048
#define I_ 256
#define H_ 256
#define G3 768

// ---------------- Phase 1 ---------------- (unchanged; ~0.75 ms, 44% of fp32 peak)
__global__ __launch_bounds__(256) void gi_gemm(
    const float* __restrict__ x, const float* __restrict__ Wih,
    const float* __restrict__ bih, const float* __restrict__ bhh,
    float* __restrict__ gi, int t0)
{
  const int t  = t0 + blockIdx.x;
  const int n0 = blockIdx.y * 64;
  __shared__ float As[32][68];
  __shared__ float Bs[32][68];
  const int tid = threadIdx.x;
  const int ty = tid >> 4, tx = tid & 15;
  const int lr = tid >> 3;
  const int lk = (tid & 7) << 2;
  float acc[4][4] = {};

  for (int kc = 0; kc < I_; kc += 32) {
    float4 a0 = *(const float4*)(x + ((size_t)lr        * T_ + t) * I_ + kc + lk);
    float4 a1 = *(const float4*)(x + ((size_t)(lr + 32) * T_ + t) * I_ + kc + lk);
    float4 b0 = *(const float4*)(Wih + (size_t)(n0 + lr)      * I_ + kc + lk);
    float4 b1 = *(const float4*)(Wih + (size_t)(n0 + lr + 32) * I_ + kc + lk);
    __syncthreads();
    As[lk+0][lr]    = a0.x; As[lk+1][lr]    = a0.y; As[lk+2][lr]    = a0.z; As[lk+3][lr]    = a0.w;
    As[lk+0][lr+32] = a1.x; As[lk+1][lr+32] = a1.y; As[lk+2][lr+32] = a1.z; As[lk+3][lr+32] = a1.w;
    Bs[lk+0][lr]    = b0.x; Bs[lk+1][lr]    = b0.y; Bs[lk+2][lr]    = b0.z; Bs[lk+3][lr]    = b0.w;
    Bs[lk+0][lr+32] = b1.x; Bs[lk+1][lr+32] = b1.y; Bs[lk+2][lr+32] = b1.z; Bs[lk+3][lr+32] = b1.w;
    __syncthreads();
    #pragma unroll
    for (int kk = 0; kk < 32; ++kk) {
      float4 av = *(const float4*)(&As[kk][ty << 2]);
      float4 bv = *(const float4*)(&Bs[kk][tx << 2]);
      float av_[4] = {av.x, av.y, av.z, av.w};
      float bv_[4] = {bv.x, bv.y, bv.z, bv.w};
      #pragma unroll
      for (int i = 0; i < 4; ++i)
        #pragma unroll
        for (int u = 0; u < 4; ++u)
          acc[i][u] = fmaf(av_[i], bv_[u], acc[i][u]);
    }
  }

  const int colb = n0 + (tx << 2);
  float4 bi = *(const float4*)(bih + colb);
  float4 bh = *(const float4*)(bhh + colb);
  float4 badd;
  badd.x = bi.x + (colb + 0 < 512 ? bh.x : 0.f);
  badd.y = bi.y + (colb + 1 < 512 ? bh.y : 0.f);
  badd.z = bi.z + (colb + 2 < 512 ? bh.z : 0.f);
  badd.w = bi.w + (colb + 3 < 512 ? bh.w : 0.f);
  float* gout = gi + (size_t)blockIdx.x * 64 * G3;
  #pragma unroll
  for (int i = 0; i < 4; ++i) {
    int bb = (ty << 2) + i;
    float4 o;
    o.x = acc[i][0] + badd.x; o.y = acc[i][1] + badd.y;
    o.z = acc[i][2] + badd.z; o.w = acc[i][3] + badd.w;
    *(float4*)(gout + (size_t)bb * G3 + colb) = o;
  }
}

// ---------------- Phase 2: paired-block recurrence ----------------
// grid = 128: block (b = bx&63, half = bx>>6) owns h rows [half*128, half*128+128)
// and the corresponding 384 rows of W_hh (128 per gate), all in VGPRs.
// 512 threads: j6 = tid>>3 in [0,64), s = tid&7 -> k-slice [32s, 32s+32).
// Thread rows: {g*256 + b0 + j6 + d*64 : g in {r,z,n}, d in {0,1}} -> 6x32 = 192 w.
// Per-step h exchange between the pair via agent-scope 64-bit atomics,
// value = (tag:32 | f32 bits:32), parity-alternating slots (ABA-safe).
__global__ __launch_bounds__(512) __attribute__((amdgpu_waves_per_eu(2, 2)))
void gru_pair(const float* __restrict__ gi, const float* __restrict__ att,
              const int* __restrict__ lengths, const float* __restrict__ Whh,
              const float* __restrict__ bhh, uint64_t* __restrict__ pub,
              float* __restrict__ hws, float* __restrict__ out, int t0, int t1)
{
  const int bx   = blockIdx.x;
  const int b    = bx & 63;
  const int half = bx >> 6;
  const int b0   = half << 7;
  const int ob0  = 128 - b0;
  const int tid  = threadIdx.x;
  const int s    = tid & 7;
  const int j6   = tid >> 3;
  const int k0   = s << 5;

  __shared__ float hbuf[2][256];

  // ---- weights: 48 float4 in VGPRs (budget pinned by waves_per_eu(2,2)) ----
  float4 w[48];
  {
    int r = 0;
    #pragma unroll
    for (int g = 0; g < 3; ++g)
      #pragma unroll
      for (int d = 0; d < 2; ++d) {
        const float* row = Whh + (size_t)(g * 256 + b0 + j6 + d * 64) * H_ + k0;
        #pragma unroll
        for (int q = 0; q < 8; ++q) w[r++] = *(const float4*)(row + (q << 2));
      }
  }

  float bhn0 = 0.f, bhn1 = 0.f, h0 = 0.f, h1 = 0.f;
  if (s == 0) {
    bhn0 = bhh[512 + b0 + j6];
    bhn1 = bhh[512 + b0 + j6 + 64];
    if (t0 > 0) {
      h0 = hws[b * H_ + b0 + j6];
      h1 = hws[b * H_ + b0 + j6 + 64];
    }
  }
  if (tid < 256) hbuf[0][tid] = (t0 > 0) ? hws[b * H_ + tid] : 0.f;
  int len = lengths[b]; if (len > t1) len = t1;
  __syncthreads();

  // gi/att pipeline (one step ahead), leader lanes (s==0) only
  float c_gr0=0.f,c_gr1=0.f,c_gz0=0.f,c_gz1=0.f,c_gn0=0.f,c_gn1=0.f,c_wat=0.f;
  if (s == 0 && t0 < len) {
    const float* gb = gi + (size_t)b * G3;
    c_gr0 = gb[b0+j6];       c_gr1 = gb[b0+j6+64];
    c_gz0 = gb[256+b0+j6];   c_gz1 = gb[256+b0+j6+64];
    c_gn0 = gb[512+b0+j6];   c_gn1 = gb[512+b0+j6+64];
    c_wat = att[(size_t)b * T_ + t0];
  }
  uint64_t*       pub_w = pub + ((size_t)b * 2 + half) * 256;
  const uint64_t* pub_r = pub + ((size_t)b * 2 + (1 - half)) * 256;

  int p = 0;
  for (int t = t0; t < len; ++t) {
    float n_gr0=0.f,n_gr1=0.f,n_gz0=0.f,n_gz1=0.f,n_gn0=0.f,n_gn1=0.f,n_wat=0.f;
    if (s == 0 && t + 1 < len) {
      const float* gb = gi + ((size_t)(t + 1 - t0) * 64 + b) * G3;
      n_gr0 = gb[b0+j6];       n_gr1 = gb[b0+j6+64];
      n_gz0 = gb[256+b0+j6];   n_gz1 = gb[256+b0+j6+64];
      n_gn0 = gb[512+b0+j6];   n_gn1 = gb[512+b0+j6+64];
      n_wat = att[(size_t)b * T_ + t + 1];
    }

    float ar0=0.f, ar1=0.f, az0=0.f, az1=0.f, an0=0.f, an1=0.f;
    const float* hb = &hbuf[p][k0];
    #pragma unroll
    for (int q = 0; q < 8; ++q) {
      float4 hv = *(const float4*)(hb + (q << 2));
      float4 v;
      v = w[q];
      ar0 = fmaf(v.x,hv.x,ar0); ar0 = fmaf(v.y,hv.y,ar0); ar0 = fmaf(v.z,hv.z,ar0); ar0 = fmaf(v.w,hv.w,ar0);
      v = w[8+q];
      ar1 = fmaf(v.x,hv.x,ar1); ar1 = fmaf(v.y,hv.y,ar1); ar1 = fmaf(v.z,hv.z,ar1); ar1 = fmaf(v.w,hv.w,ar1);
      v = w[16+q];
      az0 = fmaf(v.x,hv.x,az0); az0 = fmaf(v.y,hv.y,az0); az0 = fmaf(v.z,hv.z,az0); az0 = fmaf(v.w,hv.w,az0);
      v = w[24+q];
      az1 = fmaf(v.x,hv.x,az1); az1 = fmaf(v.y,hv.y,az1); az1 = fmaf(v.z,hv.z,az1); az1 = fmaf(v.w,hv.w,az1);
      v = w[32+q];
      an0 = fmaf(v.x,hv.x,an0); an0 = fmaf(v.y,hv.y,an0); an0 = fmaf(v.z,hv.z,an0); an0 = fmaf(v.w,hv.w,an0);
      v = w[40+q];
      an1 = fmaf(v.x,hv.x,an1); an1 = fmaf(v.y,hv.y,an1); an1 = fmaf(v.z,hv.z,an1); an1 = fmaf(v.w,hv.w,an1);
    }
    // butterfly reduce over the 8 k-slices
    #pragma unroll
    for (int m = 1; m <= 4; m <<= 1) {
      ar0 += __shfl_xor(ar0, m); ar1 += __shfl_xor(ar1, m);
      az0 += __shfl_xor(az0, m); az1 += __shfl_xor(az1, m);
      an0 += __shfl_xor(an0, m); an1 += __shfl_xor(an1, m);
    }

    const uint32_t tag = (uint32_t)(t + 1);
    const int par = (t & 1) << 7;

    if (s == 0) {
      float r0 = 1.f / (1.f + __expf(-(ar0 + c_gr0)));
      float z0 = 1.f / (1.f + __expf(-(az0 + c_gz0)));
      float e0 = __expf(2.f * (c_gn0 + r0 * (an0 + bhn0)));
      float nn0 = 1.f - 2.f / (e0 + 1.f);
      float hn0 = (1.f - z0) * nn0 + z0 * h0;
      h0 = c_wat * hn0 + (1.f - c_wat) * h0;

      float r1 = 1.f / (1.f + __expf(-(ar1 + c_gr1)));
      float z1 = 1.f / (1.f + __expf(-(az1 + c_gz1)));
      float e1 = __expf(2.f * (c_gn1 + r1 * (an1 + bhn1)));
      float nn1 = 1.f - 2.f / (e1 + 1.f);
      float hn1 = (1.f - z1) * nn1 + z1 * h1;
      h1 = c_wat * hn1 + (1.f - c_wat) * h1;

      __hip_atomic_store(&pub_w[par + j6],
          ((uint64_t)tag << 32) | (uint64_t)__float_as_uint(h0),
          __ATOMIC_RELAXED, __HIP_MEMORY_SCOPE_AGENT);
      __hip_atomic_store(&pub_w[par + j6 + 64],
          ((uint64_t)tag << 32) | (uint64_t)__float_as_uint(h1),
          __ATOMIC_RELAXED, __HIP_MEMORY_SCOPE_AGENT);
      hbuf[p ^ 1][b0 + j6]      = h0;
      hbuf[p ^ 1][b0 + j6 + 64] = h1;
    }
    __builtin_amdgcn_sched_barrier(0);   // keep publish before spin in issue order
    if (s == 1 || s == 2) {
      int idx = j6 + ((s - 1) << 6);
      uint64_t v;
      do {
        v = __hip_atomic_load(&pub_r[par + idx], __ATOMIC_RELAXED, __HIP_MEMORY_SCOPE_AGENT);
      } while ((uint32_t)(v >> 32) != tag);
      hbuf[p ^ 1][ob0 + idx] = __uint_as_float((uint32_t)v);
    }
    __syncthreads();
    p ^= 1;
    c_gr0=n_gr0; c_gr1=n_gr1; c_gz0=n_gz0; c_gz1=n_gz1;
    c_gn0=n_gn0; c_gn1=n_gn1; c_wat=n_wat;
  }

  if (s == 0) {
    hws[b * H_ + b0 + j6]      = h0;
    hws[b * H_ + b0 + j6 + 64] = h1;
    if (t1 == T_) {
      out[b * H_ + b0 + j6]      = h0;
      out[b * H_ + b0 + j6 + 64] = h1;
    }
  }
}

extern "C" void kernel_launch(void* const* d_in, const int* in_sizes, int n_in,
                              void* d_out, int out_size, void* d_ws, size_t ws_size,
                              hipStream_t stream)
{
  const float* x       = (const float*)d_in[0];
  const float* att     = (const float*)d_in[1];
  const int*   lengths = (const int*)d_in[2];
  const float* Wih     = (const float*)d_in[3];
  const float* Whh     = (const float*)d_in[4];
  const float* bih     = (const float*)d_in[5];
  const float* bhh     = (const float*)d_in[6];
  float* out = (float*)d_out;

  float*    hws = (float*)d_ws;                              // 64 KiB
  uint64_t* pub = (uint64_t*)((char*)d_ws + 65536);          // 256 KiB
  float*    gi  = (float*)((char*)d_ws + 65536 + 262144);
  const size_t used0 = 65536 + 262144;
  const size_t per_t = (size_t)B_ * G3 * sizeof(float);
  size_t avail = ws_size > used0 ? ws_size - used0 : 0;
  int Tc = (int)(avail / per_t);
  if (Tc > T_) Tc = T_;
  if (Tc < 1) Tc = 1;

  for (int t0 = 0; t0 < T_; t0 += Tc) {
    int t1 = t0 + Tc; if (t1 > T_) t1 = T_;
    dim3 g1(t1 - t0, G3 / 64);
    gi_gemm<<<g1, 256, 0, stream>>>(x, Wih, bih, bhh, gi, t0);
    gru_pair<<<128, 512, 0, stream>>>(gi, att, lengths, Whh, bhh, pub, hws, out, t0, t1);
  }
}

// Round 4
// 4775.161 us; speedup vs baseline: 4.9696x; 1.1929x over previous
//
#include <hip/hip_runtime.h>
#include <stdint.h>

#define B_ 64
#define T_ 2048
#define I_ 256
#define H_ 256
#define G3 768

// ---------------- Phase 1 ---------------- (unchanged; ~0.75 ms)
__global__ __launch_bounds__(256) void gi_gemm(
    const float* __restrict__ x, const float* __restrict__ Wih,
    const float* __restrict__ bih, const float* __restrict__ bhh,
    float* __restrict__ gi, int t0)
{
  const int t  = t0 + blockIdx.x;
  const int n0 = blockIdx.y * 64;
  __shared__ float As[32][68];
  __shared__ float Bs[32][68];
  const int tid = threadIdx.x;
  const int ty = tid >> 4, tx = tid & 15;
  const int lr = tid >> 3;
  const int lk = (tid & 7) << 2;
  float acc[4][4] = {};

  for (int kc = 0; kc < I_; kc += 32) {
    float4 a0 = *(const float4*)(x + ((size_t)lr        * T_ + t) * I_ + kc + lk);
    float4 a1 = *(const float4*)(x + ((size_t)(lr + 32) * T_ + t) * I_ + kc + lk);
    float4 b0 = *(const float4*)(Wih + (size_t)(n0 + lr)      * I_ + kc + lk);
    float4 b1 = *(const float4*)(Wih + (size_t)(n0 + lr + 32) * I_ + kc + lk);
    __syncthreads();
    As[lk+0][lr]    = a0.x; As[lk+1][lr]    = a0.y; As[lk+2][lr]    = a0.z; As[lk+3][lr]    = a0.w;
    As[lk+0][lr+32] = a1.x; As[lk+1][lr+32] = a1.y; As[lk+2][lr+32] = a1.z; As[lk+3][lr+32] = a1.w;
    Bs[lk+0][lr]    = b0.x; Bs[lk+1][lr]    = b0.y; Bs[lk+2][lr]    = b0.z; Bs[lk+3][lr]    = b0.w;
    Bs[lk+0][lr+32] = b1.x; Bs[lk+1][lr+32] = b1.y; Bs[lk+2][lr+32] = b1.z; Bs[lk+3][lr+32] = b1.w;
    __syncthreads();
    #pragma unroll
    for (int kk = 0; kk < 32; ++kk) {
      float4 av = *(const float4*)(&As[kk][ty << 2]);
      float4 bv = *(const float4*)(&Bs[kk][tx << 2]);
      float av_[4] = {av.x, av.y, av.z, av.w};
      float bv_[4] = {bv.x, bv.y, bv.z, bv.w};
      #pragma unroll
      for (int i = 0; i < 4; ++i)
        #pragma unroll
        for (int u = 0; u < 4; ++u)
          acc[i][u] = fmaf(av_[i], bv_[u], acc[i][u]);
    }
  }

  const int colb = n0 + (tx << 2);
  float4 bi = *(const float4*)(bih + colb);
  float4 bh = *(const float4*)(bhh + colb);
  float4 badd;
  badd.x = bi.x + (colb + 0 < 512 ? bh.x : 0.f);
  badd.y = bi.y + (colb + 1 < 512 ? bh.y : 0.f);
  badd.z = bi.z + (colb + 2 < 512 ? bh.z : 0.f);
  badd.w = bi.w + (colb + 3 < 512 ? bh.w : 0.f);
  float* gout = gi + (size_t)blockIdx.x * 64 * G3;
  #pragma unroll
  for (int i = 0; i < 4; ++i) {
    int bb = (ty << 2) + i;
    float4 o;
    o.x = acc[i][0] + badd.x; o.y = acc[i][1] + badd.y;
    o.z = acc[i][2] + badd.z; o.w = acc[i][3] + badd.w;
    *(float4*)(gout + (size_t)bb * G3 + colb) = o;
  }
}

// ---------------- Phase 2: paired-block recurrence, split-k two-phase ----------------
// grid = 128: block (b = bx&63, half = bx>>6) owns h rows [b0, b0+128), b0 = half*128.
// 512 threads: j6 = tid>>3 in [0,64), s = tid&7.
// Thread rows {g*256 + b0 + j6 + 64d}; k split: own [b0+16s,+16) + partner [ob0+16s,+16).
// Step: [poll issue] PhaseA(own-k FMA) [poll check->LDS] barrierA PhaseB(partner-k FMA)
//       reduce, activation, publish(tag t+1), write own LDS, barrierB.
// LDS h layout: slice stride 36 floats (16B aligned, banks 4*(9s+q)%32 distinct).
__global__ __launch_bounds__(512) __attribute__((amdgpu_waves_per_eu(2, 2)))
void gru_pair(const float* __restrict__ gi, const float* __restrict__ att,
              const int* __restrict__ lengths, const float* __restrict__ Whh,
              const float* __restrict__ bhh, uint64_t* __restrict__ pub,
              float* __restrict__ hws, float* __restrict__ out, int t0, int t1)
{
  const int bx   = blockIdx.x;
  const int b    = bx & 63;
  const int half = bx >> 6;
  const int b0   = half << 7;
  const int ob0  = 128 - b0;
  const int tid  = threadIdx.x;
  const int s    = tid & 7;
  const int j6   = tid >> 3;

  __shared__ float hown[8 * 36];
  __shared__ float hpart[8 * 36];

  // ---- weights: 24+24 float4 (own-k / partner-k slices) ----
  float4 wo[24], wp[24];
  {
    int r = 0;
    #pragma unroll
    for (int g = 0; g < 3; ++g)
      #pragma unroll
      for (int d = 0; d < 2; ++d) {
        const float* row = Whh + (size_t)(g * 256 + b0 + j6 + d * 64) * H_;
        #pragma unroll
        for (int q = 0; q < 4; ++q)
          wo[r * 4 + q] = *(const float4*)(row + b0  + (s << 4) + (q << 2));
        #pragma unroll
        for (int q = 0; q < 4; ++q)
          wp[r * 4 + q] = *(const float4*)(row + ob0 + (s << 4) + (q << 2));
        r++;
      }
  }

  float bhn0 = 0.f, bhn1 = 0.f, h0 = 0.f, h1 = 0.f;
  if (s == 0) {
    bhn0 = bhh[512 + b0 + j6];
    bhn1 = bhh[512 + b0 + j6 + 64];
    if (t0 > 0) {
      h0 = hws[b * H_ + b0 + j6];
      h1 = hws[b * H_ + b0 + j6 + 64];
    }
  }
  if (tid < 128) {
    float v = (t0 > 0) ? hws[b * H_ + b0 + tid] : 0.f;
    hown[(tid >> 4) * 36 + (tid & 15)] = v;
  } else if (tid < 256) {
    int i = tid - 128;
    float v = (t0 > 0) ? hws[b * H_ + ob0 + i] : 0.f;
    hpart[(i >> 4) * 36 + (i & 15)] = v;
  }
  int len = lengths[b]; if (len > t1) len = t1;
  __syncthreads();

  // gi/att pipeline (one step ahead), leader lanes (s==0) only
  float c_gr0=0.f,c_gr1=0.f,c_gz0=0.f,c_gz1=0.f,c_gn0=0.f,c_gn1=0.f,c_wat=0.f;
  if (s == 0 && t0 < len) {
    const float* gb = gi + (size_t)b * G3;
    c_gr0 = gb[b0+j6];       c_gr1 = gb[b0+j6+64];
    c_gz0 = gb[256+b0+j6];   c_gz1 = gb[256+b0+j6+64];
    c_gn0 = gb[512+b0+j6];   c_gn1 = gb[512+b0+j6+64];
    c_wat = att[(size_t)b * T_ + t0];
  }
  uint64_t*       pub_w = pub + ((size_t)b * 2 + half) * 256;
  const uint64_t* pub_r = pub + ((size_t)b * 2 + (1 - half)) * 256;

  const bool isp  = (s == 1) || (s == 2);
  const int  pidx = j6 + ((s - 1) << 6);     // meaningful only when isp

  for (int t = t0; t < len; ++t) {
    // ---- poll issue (latency overlaps Phase A) ----
    const bool do_poll = isp && (t > t0);
    const uint64_t* myslot = pub_r + (((t - 1) & 1) << 7) + pidx;
    uint64_t pv = 0;
    if (do_poll)
      pv = __hip_atomic_load(myslot, __ATOMIC_RELAXED, __HIP_MEMORY_SCOPE_AGENT);

    // ---- gi prefetch for t+1 ----
    float n_gr0=0.f,n_gr1=0.f,n_gz0=0.f,n_gz1=0.f,n_gn0=0.f,n_gn1=0.f,n_wat=0.f;
    if (s == 0 && t + 1 < len) {
      const float* gb = gi + ((size_t)(t + 1 - t0) * 64 + b) * G3;
      n_gr0 = gb[b0+j6];       n_gr1 = gb[b0+j6+64];
      n_gz0 = gb[256+b0+j6];   n_gz1 = gb[256+b0+j6+64];
      n_gn0 = gb[512+b0+j6];   n_gn1 = gb[512+b0+j6+64];
      n_wat = att[(size_t)b * T_ + t + 1];
    }

    float ar0=0.f, ar1=0.f, az0=0.f, az1=0.f, an0=0.f, an1=0.f;

    // ---- Phase A: own-half k ----
    {
      const float* ho = hown + s * 36;
      #pragma unroll
      for (int q = 0; q < 4; ++q) {
        float4 hv = *(const float4*)(ho + (q << 2));
        float4 v;
        v = wo[q];
        ar0 = fmaf(v.x,hv.x,ar0); ar0 = fmaf(v.y,hv.y,ar0); ar0 = fmaf(v.z,hv.z,ar0); ar0 = fmaf(v.w,hv.w,ar0);
        v = wo[4+q];
        ar1 = fmaf(v.x,hv.x,ar1); ar1 = fmaf(v.y,hv.y,ar1); ar1 = fmaf(v.z,hv.z,ar1); ar1 = fmaf(v.w,hv.w,ar1);
        v = wo[8+q];
        az0 = fmaf(v.x,hv.x,az0); az0 = fmaf(v.y,hv.y,az0); az0 = fmaf(v.z,hv.z,az0); az0 = fmaf(v.w,hv.w,az0);
        v = wo[12+q];
        az1 = fmaf(v.x,hv.x,az1); az1 = fmaf(v.y,hv.y,az1); az1 = fmaf(v.z,hv.z,az1); az1 = fmaf(v.w,hv.w,az1);
        v = wo[16+q];
        an0 = fmaf(v.x,hv.x,an0); an0 = fmaf(v.y,hv.y,an0); an0 = fmaf(v.z,hv.z,an0); an0 = fmaf(v.w,hv.w,an0);
        v = wo[20+q];
        an1 = fmaf(v.x,hv.x,an1); an1 = fmaf(v.y,hv.y,an1); an1 = fmaf(v.z,hv.z,an1); an1 = fmaf(v.w,hv.w,an1);
      }
    }

    // ---- poll check & partner LDS write ----
    if (do_poll) {
      while ((uint32_t)(pv >> 32) != (uint32_t)t)
        pv = __hip_atomic_load(myslot, __ATOMIC_RELAXED, __HIP_MEMORY_SCOPE_AGENT);
      hpart[(pidx >> 4) * 36 + (pidx & 15)] = __uint_as_float((uint32_t)pv);
    }
    __syncthreads();   // barrier A: hpart ready

    // ---- Phase B: partner-half k ----
    {
      const float* hp = hpart + s * 36;
      #pragma unroll
      for (int q = 0; q < 4; ++q) {
        float4 hv = *(const float4*)(hp + (q << 2));
        float4 v;
        v = wp[q];
        ar0 = fmaf(v.x,hv.x,ar0); ar0 = fmaf(v.y,hv.y,ar0); ar0 = fmaf(v.z,hv.z,ar0); ar0 = fmaf(v.w,hv.w,ar0);
        v = wp[4+q];
        ar1 = fmaf(v.x,hv.x,ar1); ar1 = fmaf(v.y,hv.y,ar1); ar1 = fmaf(v.z,hv.z,ar1); ar1 = fmaf(v.w,hv.w,ar1);
        v = wp[8+q];
        az0 = fmaf(v.x,hv.x,az0); az0 = fmaf(v.y,hv.y,az0); az0 = fmaf(v.z,hv.z,az0); az0 = fmaf(v.w,hv.w,az0);
        v = wp[12+q];
        az1 = fmaf(v.x,hv.x,az1); az1 = fmaf(v.y,hv.y,az1); az1 = fmaf(v.z,hv.z,az1); az1 = fmaf(v.w,hv.w,az1);
        v = wp[16+q];
        an0 = fmaf(v.x,hv.x,an0); an0 = fmaf(v.y,hv.y,an0); an0 = fmaf(v.z,hv.z,an0); an0 = fmaf(v.w,hv.w,an0);
        v = wp[20+q];
        an1 = fmaf(v.x,hv.x,an1); an1 = fmaf(v.y,hv.y,an1); an1 = fmaf(v.z,hv.z,an1); an1 = fmaf(v.w,hv.w,an1);
      }
    }

    // ---- reduce over the 8 k-slices ----
    #pragma unroll
    for (int m = 1; m <= 4; m <<= 1) {
      ar0 += __shfl_xor(ar0, m); ar1 += __shfl_xor(ar1, m);
      az0 += __shfl_xor(az0, m); az1 += __shfl_xor(az1, m);
      an0 += __shfl_xor(an0, m); an1 += __shfl_xor(an1, m);
    }

    const uint32_t tag = (uint32_t)(t + 1);
    const int par = (t & 1) << 7;

    if (s == 0) {
      float r0 = 1.f / (1.f + __expf(-(ar0 + c_gr0)));
      float z0 = 1.f / (1.f + __expf(-(az0 + c_gz0)));
      float e0 = __expf(2.f * (c_gn0 + r0 * (an0 + bhn0)));
      float nn0 = 1.f - 2.f / (e0 + 1.f);
      float hn0 = (1.f - z0) * nn0 + z0 * h0;
      h0 = c_wat * hn0 + (1.f - c_wat) * h0;

      float r1 = 1.f / (1.f + __expf(-(ar1 + c_gr1)));
      float z1 = 1.f / (1.f + __expf(-(az1 + c_gz1)));
      float e1 = __expf(2.f * (c_gn1 + r1 * (an1 + bhn1)));
      float nn1 = 1.f - 2.f / (e1 + 1.f);
      float hn1 = (1.f - z1) * nn1 + z1 * h1;
      h1 = c_wat * hn1 + (1.f - c_wat) * h1;

      // publish first (partner is waiting on these)
      __hip_atomic_store(&pub_w[par + j6],
          ((uint64_t)tag << 32) | (uint64_t)__float_as_uint(h0),
          __ATOMIC_RELAXED, __HIP_MEMORY_SCOPE_AGENT);
      __hip_atomic_store(&pub_w[par + j6 + 64],
          ((uint64_t)tag << 32) | (uint64_t)__float_as_uint(h1),
          __ATOMIC_RELAXED, __HIP_MEMORY_SCOPE_AGENT);
      hown[(j6 >> 4) * 36 + (j6 & 15)] = h0;
      hown[(((j6 + 64) >> 4)) * 36 + (j6 & 15)] = h1;
    }
    __syncthreads();   // barrier B: hown ready for next Phase A
    c_gr0=n_gr0; c_gr1=n_gr1; c_gz0=n_gz0; c_gz1=n_gz1;
    c_gn0=n_gn0; c_gn1=n_gn1; c_wat=n_wat;
  }

  if (s == 0) {
    hws[b * H_ + b0 + j6]      = h0;
    hws[b * H_ + b0 + j6 + 64] = h1;
    if (t1 == T_) {
      out[b * H_ + b0 + j6]      = h0;
      out[b * H_ + b0 + j6 + 64] = h1;
    }
  }
}

extern "C" void kernel_launch(void* const* d_in, const int* in_sizes, int n_in,
                              void* d_out, int out_size, void* d_ws, size_t ws_size,
                              hipStream_t stream)
{
  const float* x       = (const float*)d_in[0];
  const float* att     = (const float*)d_in[1];
  const int*   lengths = (const int*)d_in[2];
  const float* Wih     = (const float*)d_in[3];
  const float* Whh     = (const float*)d_in[4];
  const float* bih     = (const float*)d_in[5];
  const float* bhh     = (const float*)d_in[6];
  float* out = (float*)d_out;

  float*    hws = (float*)d_ws;                              // 64 KiB
  uint64_t* pub = (uint64_t*)((char*)d_ws + 65536);          // 256 KiB
  float*    gi  = (float*)((char*)d_ws + 65536 + 262144);
  const size_t used0 = 65536 + 262144;
  const size_t per_t = (size_t)B_ * G3 * sizeof(float);
  size_t avail = ws_size > used0 ? ws_size - used0 : 0;
  int Tc = (int)(avail / per_t);
  if (Tc > T_) Tc = T_;
  if (Tc < 1) Tc = 1;

  for (int t0 = 0; t0 < T_; t0 += Tc) {
    int t1 = t0 + Tc; if (t1 > T_) t1 = T_;
    dim3 g1(t1 - t0, G3 / 64);
    gi_gemm<<<g1, 256, 0, stream>>>(x, Wih, bih, bhh, gi, t0);
    gru_pair<<<128, 512, 0, stream>>>(gi, att, lengths, Whh, bhh, pub, hws, out, t0, t1);
  }
}

// Round 6
// 3421.417 us; speedup vs baseline: 6.9359x; 1.3957x over previous
//
#include <hip/hip_runtime.h>
#include <stdint.h>

#define B_ 64
#define T_ 2048
#define I_ 256
#define H_ 256
#define G3 768

typedef _Float16 half2v __attribute__((ext_vector_type(2)));
typedef _Float16 half8v __attribute__((ext_vector_type(8)));

#if __has_builtin(__builtin_amdgcn_fdot2)
#define FDOT2(a, b, c) __builtin_amdgcn_fdot2((a), (b), (c), false)
#else
#define FDOT2(a, b, c) fmaf((float)(a)[1], (float)(b)[1], fmaf((float)(a)[0], (float)(b)[0], (c)))
#endif

// ---------------- Phase 1 ---------------- (unchanged; ~0.75 ms)
__global__ __launch_bounds__(256) void gi_gemm(
    const float* __restrict__ x, const float* __restrict__ Wih,
    const float* __restrict__ bih, const float* __restrict__ bhh,
    float* __restrict__ gi, int t0)
{
  const int t  = t0 + blockIdx.x;
  const int n0 = blockIdx.y * 64;
  __shared__ float As[32][68];
  __shared__ float Bs[32][68];
  const int tid = threadIdx.x;
  const int ty = tid >> 4, tx = tid & 15;
  const int lr = tid >> 3;
  const int lk = (tid & 7) << 2;
  float acc[4][4] = {};

  for (int kc = 0; kc < I_; kc += 32) {
    float4 a0 = *(const float4*)(x + ((size_t)lr        * T_ + t) * I_ + kc + lk);
    float4 a1 = *(const float4*)(x + ((size_t)(lr + 32) * T_ + t) * I_ + kc + lk);
    float4 b0 = *(const float4*)(Wih + (size_t)(n0 + lr)      * I_ + kc + lk);
    float4 b1 = *(const float4*)(Wih + (size_t)(n0 + lr + 32) * I_ + kc + lk);
    __syncthreads();
    As[lk+0][lr]    = a0.x; As[lk+1][lr]    = a0.y; As[lk+2][lr]    = a0.z; As[lk+3][lr]    = a0.w;
    As[lk+0][lr+32] = a1.x; As[lk+1][lr+32] = a1.y; As[lk+2][lr+32] = a1.z; As[lk+3][lr+32] = a1.w;
    Bs[lk+0][lr]    = b0.x; Bs[lk+1][lr]    = b0.y; Bs[lk+2][lr]    = b0.z; Bs[lk+3][lr]    = b0.w;
    Bs[lk+0][lr+32] = b1.x; Bs[lk+1][lr+32] = b1.y; Bs[lk+2][lr+32] = b1.z; Bs[lk+3][lr+32] = b1.w;
    __syncthreads();
    #pragma unroll
    for (int kk = 0; kk < 32; ++kk) {
      float4 av = *(const float4*)(&As[kk][ty << 2]);
      float4 bv = *(const float4*)(&Bs[kk][tx << 2]);
      float av_[4] = {av.x, av.y, av.z, av.w};
      float bv_[4] = {bv.x, bv.y, bv.z, bv.w};
      #pragma unroll
      for (int i = 0; i < 4; ++i)
        #pragma unroll
        for (int u = 0; u < 4; ++u)
          acc[i][u] = fmaf(av_[i], bv_[u], acc[i][u]);
    }
  }

  const int colb = n0 + (tx << 2);
  float4 bi = *(const float4*)(bih + colb);
  float4 bh = *(const float4*)(bhh + colb);
  float4 badd;
  badd.x = bi.x + (colb + 0 < 512 ? bh.x : 0.f);
  badd.y = bi.y + (colb + 1 < 512 ? bh.y : 0.f);
  badd.z = bi.z + (colb + 2 < 512 ? bh.z : 0.f);
  badd.w = bi.w + (colb + 3 < 512 ? bh.w : 0.f);
  float* gout = gi + (size_t)blockIdx.x * 64 * G3;
  #pragma unroll
  for (int i = 0; i < 4; ++i) {
    int bb = (ty << 2) + i;
    float4 o;
    o.x = acc[i][0] + badd.x; o.y = acc[i][1] + badd.y;
    o.z = acc[i][2] + badd.z; o.w = acc[i][3] + badd.w;
    *(float4*)(gout + (size_t)bb * G3 + colb) = o;
  }
}

// ---------------- Phase 2: single-block recurrence, fp16 dot2 ----------------
// grid = 64 (one block per batch). 512 threads: j = tid>>1 in [0,256), s = tid&1,
// k-half [128s, 128s+128). Thread rows {j, 256+j, 512+j} -> 3*128 halves = 192
// packed half2 regs (overflow -> AGPRs; gfx950 VALU reads AGPRs directly).
// h: fp32 carry in leader regs; fp16 copy in LDS (double buffer, slice stride
// 136 halves => ds_read_b128 banks disjoint across s). One barrier per step.
// No cross-CU exchange at all.
__global__ __launch_bounds__(512) __attribute__((amdgpu_waves_per_eu(2, 2)))
void gru_seq16(const float* __restrict__ gi, const float* __restrict__ att,
               const int* __restrict__ lengths, const float* __restrict__ Whh,
               const float* __restrict__ bhh, float* __restrict__ hws,
               float* __restrict__ out, int t0, int t1)
{
  const int b   = blockIdx.x;
  const int tid = threadIdx.x;
  const int j   = tid >> 1;
  const int s   = tid & 1;
  const int k0  = s << 7;

  __shared__ _Float16 hbuf[2][272];   // 2 slices * 136 (pad 8), double buffered

  // ---- convert W_hh rows to packed fp16 in registers (prologue only) ----
  half2v w[192];
  #pragma unroll
  for (int g = 0; g < 3; ++g) {
    const float* row = Whh + (size_t)(g * 256 + j) * H_ + k0;
    #pragma unroll
    for (int q = 0; q < 32; ++q) {
      float4 v = *(const float4*)(row + (q << 2));
      half2v a, c;
      a[0] = (_Float16)v.x; a[1] = (_Float16)v.y;
      c[0] = (_Float16)v.z; c[1] = (_Float16)v.w;
      w[g * 64 + 2 * q]     = a;
      w[g * 64 + 2 * q + 1] = c;
    }
  }

  float bhn = 0.f, h_reg = 0.f;
  if (s == 0) {
    bhn = bhh[512 + j];
    h_reg = (t0 > 0) ? hws[b * H_ + j] : 0.f;
  }
  if (tid < 256) {
    float v = (t0 > 0) ? hws[b * H_ + tid] : 0.f;
    hbuf[0][(tid >> 7) * 136 + (tid & 127)] = (_Float16)v;
  }
  int len = lengths[b]; if (len > t1) len = t1;
  __syncthreads();

  // gi/att pipeline (one step ahead), leader lanes (s==0)
  float c_gr = 0.f, c_gz = 0.f, c_gn = 0.f, c_wat = 0.f;
  if (s == 0 && t0 < len) {
    const float* gb = gi + (size_t)b * G3;
    c_gr = gb[j]; c_gz = gb[256 + j]; c_gn = gb[512 + j];
    c_wat = att[(size_t)b * T_ + t0];
  }

  int p = 0;
  for (int t = t0; t < len; ++t) {
    float n_gr = 0.f, n_gz = 0.f, n_gn = 0.f, n_wat = 0.f;
    if (s == 0 && t + 1 < len) {
      const float* gb = gi + ((size_t)(t + 1 - t0) * 64 + b) * G3;
      n_gr = gb[j]; n_gz = gb[256 + j]; n_gn = gb[512 + j];
      n_wat = att[(size_t)b * T_ + t + 1];
    }

    float accr = 0.f, accz = 0.f, accn = 0.f;
    const _Float16* hb = &hbuf[p][s * 136];
    #pragma unroll
    for (int q = 0; q < 16; ++q) {
      half8v hv = *(const half8v*)(hb + (q << 3));
      half2v h0 = __builtin_shufflevector(hv, hv, 0, 1);
      half2v h1 = __builtin_shufflevector(hv, hv, 2, 3);
      half2v h2 = __builtin_shufflevector(hv, hv, 4, 5);
      half2v h3 = __builtin_shufflevector(hv, hv, 6, 7);
      const int qq = q << 2;
      accr = FDOT2(w[qq + 0], h0, accr);
      accr = FDOT2(w[qq + 1], h1, accr);
      accr = FDOT2(w[qq + 2], h2, accr);
      accr = FDOT2(w[qq + 3], h3, accr);
      accz = FDOT2(w[64 + qq + 0], h0, accz);
      accz = FDOT2(w[64 + qq + 1], h1, accz);
      accz = FDOT2(w[64 + qq + 2], h2, accz);
      accz = FDOT2(w[64 + qq + 3], h3, accz);
      accn = FDOT2(w[128 + qq + 0], h0, accn);
      accn = FDOT2(w[128 + qq + 1], h1, accn);
      accn = FDOT2(w[128 + qq + 2], h2, accn);
      accn = FDOT2(w[128 + qq + 3], h3, accn);
    }
    // reduce over the 2 k-halves (adjacent lanes)
    accr += __shfl_xor(accr, 1);
    accz += __shfl_xor(accz, 1);
    accn += __shfl_xor(accn, 1);

    if (s == 0) {
      float r = 1.f / (1.f + __expf(-(accr + c_gr)));
      float z = 1.f / (1.f + __expf(-(accz + c_gz)));
      float e2 = __expf(2.f * (c_gn + r * (accn + bhn)));
      float nn = 1.f - 2.f / (e2 + 1.f);      // tanh
      float hnew = (1.f - z) * nn + z * h_reg;
      h_reg = c_wat * hnew + (1.f - c_wat) * h_reg;
      hbuf[p ^ 1][(j >> 7) * 136 + (j & 127)] = (_Float16)h_reg;
    }
    __syncthreads();
    p ^= 1;
    c_gr = n_gr; c_gz = n_gz; c_gn = n_gn; c_wat = n_wat;
  }

  if (s == 0) {
    hws[b * H_ + j] = h_reg;
    if (t1 == T_) out[b * H_ + j] = h_reg;
  }
}

extern "C" void kernel_launch(void* const* d_in, const int* in_sizes, int n_in,
                              void* d_out, int out_size, void* d_ws, size_t ws_size,
                              hipStream_t stream)
{
  const float* x       = (const float*)d_in[0];
  const float* att     = (const float*)d_in[1];
  const int*   lengths = (const int*)d_in[2];
  const float* Wih     = (const float*)d_in[3];
  const float* Whh     = (const float*)d_in[4];
  const float* bih     = (const float*)d_in[5];
  const float* bhh     = (const float*)d_in[6];
  float* out = (float*)d_out;

  float* hws = (float*)d_ws;                         // 64 KiB
  float* gi  = (float*)((char*)d_ws + 65536);
  const size_t used0 = 65536;
  const size_t per_t = (size_t)B_ * G3 * sizeof(float);
  size_t avail = ws_size > used0 ? ws_size - used0 : 0;
  int Tc = (int)(avail / per_t);
  if (Tc > T_) Tc = T_;
  if (Tc < 1) Tc = 1;

  for (int t0 = 0; t0 < T_; t0 += Tc) {
    int t1 = t0 + Tc; if (t1 > T_) t1 = T_;
    dim3 g1(t1 - t0, G3 / 64);
    gi_gemm<<<g1, 256, 0, stream>>>(x, Wih, bih, bhh, gi, t0);
    gru_seq16<<<B_, 512, 0, stream>>>(gi, att, lengths, Whh, bhh, hws, out, t0, t1);
  }
}